// Round 15
// baseline (358.535 us; speedup 1.0000x reference)
//
#include <hip/hip_runtime.h>
#include <math.h>

#define NN 4096      // nodes
#define NG 16        // graphs
#define WB() __builtin_amdgcn_wave_barrier()

// ---------------------------------------------------------------- CSR prep
__global__ void rowptr3_kernel(const int* __restrict__ ea, int Ea,
                               const int* __restrict__ eb, int Eb,
                               const int* __restrict__ ec, int Ec,
                               int* __restrict__ rpa, int* __restrict__ rpb, int* __restrict__ rpc){
    int t = blockIdx.x * blockDim.x + threadIdx.x;
    int set = t / (NN + 1), i = t % (NN + 1);
    if (set >= 3) return;
    const int* e0 = set == 0 ? ea : set == 1 ? eb : ec;
    int E        = set == 0 ? Ea : set == 1 ? Eb : Ec;
    int* rp      = set == 0 ? rpa : set == 1 ? rpb : rpc;
    if (i == NN){ rp[NN] = E; return; }
    int lo = 0, hi = E;
    while (lo < hi){ int mid = (lo + hi) >> 1; if (e0[mid] < i) lo = mid + 1; else hi = mid; }
    rp[i] = lo;
}

__global__ void dinv2_kernel(const int* __restrict__ rp1, const int* __restrict__ rp2,
                             float* __restrict__ dinv1, float* __restrict__ dinv2){
    int t = blockIdx.x * blockDim.x + threadIdx.x;
    int set = t >> 12, i = t & (NN - 1);
    if (set >= 2) return;
    const int* rp = set ? rp2 : rp1;
    float deg = (float)(rp[i+1] - rp[i] + 1);          // +1 self loop
    (set ? dinv2 : dinv1)[i] = 1.0f / sqrtf(deg);
}

// per-head global max of al (valid softmax-stabilizer upper bound for any dst)
template<int NH>
__global__ __launch_bounds__(256)
void max_al_kernel(const float* __restrict__ al, int n, float* __restrict__ M){
    __shared__ float red[4 * NH];
    float mx[NH];
    #pragma unroll
    for (int h = 0; h < NH; ++h) mx[h] = -1e30f;
    for (int r = threadIdx.x; r < n; r += 256)
        #pragma unroll
        for (int h = 0; h < NH; ++h) mx[h] = fmaxf(mx[h], al[(size_t)r*NH + h]);
    #pragma unroll
    for (int h = 0; h < NH; ++h){
        float v = mx[h];
        #pragma unroll
        for (int off = 1; off < 64; off <<= 1) v = fmaxf(v, __shfl_xor(v, off));
        if ((threadIdx.x & 63) == 0) red[(threadIdx.x >> 6) * NH + h] = v;
    }
    __syncthreads();
    if (threadIdx.x < NH){
        float m = fmaxf(fmaxf(red[0*NH + threadIdx.x], red[1*NH + threadIdx.x]),
                        fmaxf(red[2*NH + threadIdx.x], red[3*NH + threadIdx.x]));
        M[threadIdx.x] = m;
    }
}

// ---------------------------------------------------------------- dense GEMM (64-row tile)
__global__ __launch_bounds__(256)
void gemm_kernel(const float* __restrict__ A, const float* __restrict__ W,
                 const float* __restrict__ bias, float* __restrict__ C,
                 int K, int Nc, int act){
    __shared__ float As[64][17];
    __shared__ float Bs[16][64];
    const int tid = threadIdx.x;
    const int tx = tid & 15, ty = tid >> 4;
    const int row0 = blockIdx.y * 64, col0 = blockIdx.x * 64;
    float acc[4][4] = {};
    for (int k0 = 0; k0 < K; k0 += 16){
        {   int idx = tid * 4; int r = idx >> 4, kk = idx & 15;
            float4 av = *reinterpret_cast<const float4*>(&A[(size_t)(row0 + r) * K + k0 + kk]);
            As[r][kk+0]=av.x; As[r][kk+1]=av.y; As[r][kk+2]=av.z; As[r][kk+3]=av.w; }
        {   int idx = tid * 4; int r = idx >> 6, cc = idx & 63;
            float4 wv = *reinterpret_cast<const float4*>(&W[(size_t)(k0 + r) * Nc + col0 + cc]);
            *reinterpret_cast<float4*>(&Bs[r][cc]) = wv; }
        __syncthreads();
        #pragma unroll
        for (int kk = 0; kk < 16; ++kk){
            float a[4], b[4];
            #pragma unroll
            for (int i = 0; i < 4; ++i) a[i] = As[ty*4+i][kk];
            #pragma unroll
            for (int j = 0; j < 4; ++j) b[j] = Bs[kk][tx*4+j];
            #pragma unroll
            for (int i = 0; i < 4; ++i)
                #pragma unroll
                for (int j = 0; j < 4; ++j) acc[i][j] += a[i]*b[j];
        }
        __syncthreads();
    }
    #pragma unroll
    for (int i = 0; i < 4; ++i){
        int r = row0 + ty*4 + i;
        #pragma unroll
        for (int j = 0; j < 4; ++j){
            int c = col0 + tx*4 + j;
            float v = acc[i][j] + (bias ? bias[c] : 0.0f);
            if (act == 1) v = fmaxf(v, 0.0f);
            C[(size_t)r * Nc + c] = v;
        }
    }
}

// GEMM (64-row tile, Nc=512) + fused 8-head attention dots
__global__ __launch_bounds__(256)
void gemm_attn8_kernel(const float* __restrict__ A, const float* __restrict__ W,
                       float* __restrict__ C,
                       const float* __restrict__ a_src, const float* __restrict__ a_dst,
                       float* __restrict__ al, float* __restrict__ ar){
    __shared__ float As[64][17];
    __shared__ float Bs[16][64];
    __shared__ float redal[64][17];
    __shared__ float redar[64][17];
    const int tid = threadIdx.x;
    const int tx = tid & 15, ty = tid >> 4;
    const int row0 = blockIdx.y * 64, col0 = blockIdx.x * 64;
    const int K = 64, Nc = 512;
    float acc[4][4] = {};
    for (int k0 = 0; k0 < K; k0 += 16){
        {   int idx = tid * 4; int r = idx >> 4, kk = idx & 15;
            float4 av = *reinterpret_cast<const float4*>(&A[(size_t)(row0 + r) * K + k0 + kk]);
            As[r][kk+0]=av.x; As[r][kk+1]=av.y; As[r][kk+2]=av.z; As[r][kk+3]=av.w; }
        {   int idx = tid * 4; int r = idx >> 6, cc = idx & 63;
            float4 wv = *reinterpret_cast<const float4*>(&W[(size_t)(k0 + r) * Nc + col0 + cc]);
            *reinterpret_cast<float4*>(&Bs[r][cc]) = wv; }
        __syncthreads();
        #pragma unroll
        for (int kk = 0; kk < 16; ++kk){
            float a[4], b[4];
            #pragma unroll
            for (int i = 0; i < 4; ++i) a[i] = As[ty*4+i][kk];
            #pragma unroll
            for (int j = 0; j < 4; ++j) b[j] = Bs[kk][tx*4+j];
            #pragma unroll
            for (int i = 0; i < 4; ++i)
                #pragma unroll
                for (int j = 0; j < 4; ++j) acc[i][j] += a[i]*b[j];
        }
        __syncthreads();
    }
    float pal[4] = {0.f,0.f,0.f,0.f}, par[4] = {0.f,0.f,0.f,0.f};
    #pragma unroll
    for (int j = 0; j < 4; ++j){
        int c = col0 + tx*4 + j;
        float as = a_src[c], ad = a_dst[c];
        #pragma unroll
        for (int i = 0; i < 4; ++i){
            pal[i] += acc[i][j] * as;
            par[i] += acc[i][j] * ad;
        }
    }
    #pragma unroll
    for (int i = 0; i < 4; ++i){
        int r = row0 + ty*4 + i;
        #pragma unroll
        for (int j = 0; j < 4; ++j)
            C[(size_t)r * Nc + col0 + tx*4 + j] = acc[i][j];
        redal[ty*4+i][tx] = pal[i];
        redar[ty*4+i][tx] = par[i];
    }
    __syncthreads();
    if (tid < 64){
        float sa = 0.f, sr = 0.f;
        #pragma unroll
        for (int t = 0; t < 16; ++t){ sa += redal[tid][t]; sr += redar[tid][t]; }
        al[(size_t)(row0 + tid)*8 + blockIdx.x] = sa;
        ar[(size_t)(row0 + tid)*8 + blockIdx.x] = sr;
    }
}

// 32-row tile variant for narrow GEMMs
__global__ __launch_bounds__(256)
void gemm32_kernel(const float* __restrict__ A, const float* __restrict__ W,
                   const float* __restrict__ bias, float* __restrict__ C,
                   int K, int Nc, int act){
    __shared__ float As[32][17];
    __shared__ float Bs[16][64];
    const int tid = threadIdx.x;
    const int tx = tid & 15, ty = tid >> 4;
    const int row0 = blockIdx.y * 32, col0 = blockIdx.x * 64;
    float acc[2][4] = {};
    for (int k0 = 0; k0 < K; k0 += 16){
        {   int idx = tid * 2; int r = idx >> 4, kk = idx & 15;
            float2 av = *reinterpret_cast<const float2*>(&A[(size_t)(row0 + r) * K + k0 + kk]);
            As[r][kk] = av.x; As[r][kk+1] = av.y; }
        {   int idx = tid * 4; int r = idx >> 6, cc = idx & 63;
            *reinterpret_cast<float4*>(&Bs[r][cc]) =
                *reinterpret_cast<const float4*>(&W[(size_t)(k0 + r) * Nc + col0 + cc]); }
        __syncthreads();
        #pragma unroll
        for (int kk = 0; kk < 16; ++kk){
            float a0 = As[ty*2][kk], a1 = As[ty*2+1][kk];
            float b[4];
            #pragma unroll
            for (int j = 0; j < 4; ++j) b[j] = Bs[kk][tx*4+j];
            #pragma unroll
            for (int j = 0; j < 4; ++j){ acc[0][j] += a0*b[j]; acc[1][j] += a1*b[j]; }
        }
        __syncthreads();
    }
    #pragma unroll
    for (int i = 0; i < 2; ++i){
        int r = row0 + ty*2 + i;
        #pragma unroll
        for (int j = 0; j < 4; ++j){
            int c = col0 + tx*4 + j;
            float v = acc[i][j] + (bias ? bias[c] : 0.0f);
            if (act == 1) v = fmaxf(v, 0.0f);
            C[(size_t)r * Nc + c] = v;
        }
    }
}

// 32-row GEMM (K=512, Nc=64) + fused 1-head attention dots
__global__ __launch_bounds__(256)
void gemm32_attn1_kernel(const float* __restrict__ A, const float* __restrict__ W,
                         float* __restrict__ C,
                         const float* __restrict__ a_src, const float* __restrict__ a_dst,
                         float* __restrict__ al, float* __restrict__ ar){
    __shared__ float As[32][17];
    __shared__ float Bs[16][64];
    __shared__ float redal[32][17];
    __shared__ float redar[32][17];
    const int tid = threadIdx.x;
    const int tx = tid & 15, ty = tid >> 4;
    const int row0 = blockIdx.y * 32;
    const int K = 512, Nc = 64;
    float acc[2][4] = {};
    for (int k0 = 0; k0 < K; k0 += 16){
        {   int idx = tid * 2; int r = idx >> 4, kk = idx & 15;
            float2 av = *reinterpret_cast<const float2*>(&A[(size_t)(row0 + r) * K + k0 + kk]);
            As[r][kk] = av.x; As[r][kk+1] = av.y; }
        {   int idx = tid * 4; int r = idx >> 6, cc = idx & 63;
            *reinterpret_cast<float4*>(&Bs[r][cc]) =
                *reinterpret_cast<const float4*>(&W[(size_t)(k0 + r) * Nc + cc]); }
        __syncthreads();
        #pragma unroll
        for (int kk = 0; kk < 16; ++kk){
            float a0 = As[ty*2][kk], a1 = As[ty*2+1][kk];
            float b[4];
            #pragma unroll
            for (int j = 0; j < 4; ++j) b[j] = Bs[kk][tx*4+j];
            #pragma unroll
            for (int j = 0; j < 4; ++j){ acc[0][j] += a0*b[j]; acc[1][j] += a1*b[j]; }
        }
        __syncthreads();
    }
    float pal[2] = {0.f,0.f}, par[2] = {0.f,0.f};
    #pragma unroll
    for (int j = 0; j < 4; ++j){
        int c = tx*4 + j;
        float as = a_src[c], ad = a_dst[c];
        pal[0] += acc[0][j]*as; pal[1] += acc[1][j]*as;
        par[0] += acc[0][j]*ad; par[1] += acc[1][j]*ad;
    }
    #pragma unroll
    for (int i = 0; i < 2; ++i){
        int r = row0 + ty*2 + i;
        #pragma unroll
        for (int j = 0; j < 4; ++j)
            C[(size_t)r * Nc + tx*4 + j] = acc[i][j];
        redal[ty*2+i][tx] = pal[i];
        redar[ty*2+i][tx] = par[i];
    }
    __syncthreads();
    if (tid < 32){
        float sa = 0.f, sr = 0.f;
        #pragma unroll
        for (int t = 0; t < 16; ++t){ sa += redal[tid][t]; sr += redar[tid][t]; }
        al[row0 + tid] = sa;
        ar[row0 + tid] = sr;
    }
}

// ---------------------------------------------------------------- GAT1 agg, channel-split, single-pass
// m = leaky_relu(M[h] + ar_i) (global-bound stabilizer, softmax-invariant);
// normalizer s accumulated IN phase 2 (each edge's weight counted once).
__global__ __launch_bounds__(64)
void gat_agg8_p2_kernel(const float* __restrict__ hfeat,
                        const float* __restrict__ al, const float* __restrict__ ar,
                        const float* __restrict__ M8,
                        const int* __restrict__ rpA, const int* __restrict__ rpB, const int* __restrict__ rpC,
                        const int* __restrict__ clA, const int* __restrict__ clB, const int* __restrict__ clC,
                        const float* __restrict__ bias, float* __restrict__ out){
    const int bid = blockIdx.x;
    const int g = bid >> 1, half = bid & 1;
    const int set = g >> 12, i = g & (NN - 1);
    const int lane = threadIdx.x;
    const int* rowptr = set == 0 ? rpA : set == 1 ? rpB : rpC;
    const int* cols   = set == 0 ? clA : set == 1 ? clB : clC;
    const int start = rowptr[i], end = rowptr[i+1];
    const int deg = end - start;
    const int hb = half * 4;
    const int c0 = half * 256 + 4 * lane;
    const int hr = lane >> 4;

    float4 arv = *reinterpret_cast<const float4*>(&ar[(size_t)i*8 + hb]);
    float ar_i[4] = {arv.x, arv.y, arv.z, arv.w};
    float4 alv = *reinterpret_cast<const float4*>(&al[(size_t)i*8 + hb]);
    float al_i[4] = {alv.x, alv.y, alv.z, alv.w};
    float4 Mv = *reinterpret_cast<const float4*>(&M8[hb]);
    float Ma[4] = {Mv.x, Mv.y, Mv.z, Mv.w};
    float mh[4];
    #pragma unroll
    for (int h = 0; h < 4; ++h){
        float t = Ma[h] + ar_i[h];
        mh[h] = t >= 0.f ? t : 0.2f * t;      // lr monotone => >= all neighborhood logits
    }

    __shared__ int   sbuf[64];
    __shared__ float wbuf[64][5];
    float4 A0 = {0.f, 0.f, 0.f, 0.f};
    float sacc[4] = {0.f, 0.f, 0.f, 0.f};
    for (int k0 = 0; k0 < deg; k0 += 64){
        int cnt = min(64, deg - k0);
        if (lane < cnt){
            int j = cols[start + k0 + lane];
            sbuf[lane] = j;
            float4 av = *reinterpret_cast<const float4*>(&al[(size_t)j*8 + hb]);
            float a4[4] = {av.x, av.y, av.z, av.w};
            #pragma unroll
            for (int h = 0; h < 4; ++h){
                float x = a4[h] + ar_i[h];
                x = x >= 0.f ? x : 0.2f * x;
                float w = __expf(x - mh[h]);
                wbuf[lane][h] = w;
                sacc[h] += w;                  // this edge counted exactly once
            }
        }
        __syncthreads();
        int e = 0;
        for (; e + 8 <= cnt; e += 8){
            int j0 = sbuf[e],   j1 = sbuf[e+1], j2 = sbuf[e+2], j3 = sbuf[e+3];
            int j4 = sbuf[e+4], j5 = sbuf[e+5], j6 = sbuf[e+6], j7 = sbuf[e+7];
            float4 v0 = *reinterpret_cast<const float4*>(&hfeat[(size_t)j0*512 + c0]);
            float4 v1 = *reinterpret_cast<const float4*>(&hfeat[(size_t)j1*512 + c0]);
            float4 v2 = *reinterpret_cast<const float4*>(&hfeat[(size_t)j2*512 + c0]);
            float4 v3 = *reinterpret_cast<const float4*>(&hfeat[(size_t)j3*512 + c0]);
            float4 v4 = *reinterpret_cast<const float4*>(&hfeat[(size_t)j4*512 + c0]);
            float4 v5 = *reinterpret_cast<const float4*>(&hfeat[(size_t)j5*512 + c0]);
            float4 v6 = *reinterpret_cast<const float4*>(&hfeat[(size_t)j6*512 + c0]);
            float4 v7 = *reinterpret_cast<const float4*>(&hfeat[(size_t)j7*512 + c0]);
            float w0 = wbuf[e  ][hr], w1 = wbuf[e+1][hr], w2 = wbuf[e+2][hr], w3 = wbuf[e+3][hr];
            float w4 = wbuf[e+4][hr], w5 = wbuf[e+5][hr], w6 = wbuf[e+6][hr], w7 = wbuf[e+7][hr];
            A0.x += w0*v0.x; A0.y += w0*v0.y; A0.z += w0*v0.z; A0.w += w0*v0.w;
            A0.x += w1*v1.x; A0.y += w1*v1.y; A0.z += w1*v1.z; A0.w += w1*v1.w;
            A0.x += w2*v2.x; A0.y += w2*v2.y; A0.z += w2*v2.z; A0.w += w2*v2.w;
            A0.x += w3*v3.x; A0.y += w3*v3.y; A0.z += w3*v3.z; A0.w += w3*v3.w;
            A0.x += w4*v4.x; A0.y += w4*v4.y; A0.z += w4*v4.z; A0.w += w4*v4.w;
            A0.x += w5*v5.x; A0.y += w5*v5.y; A0.z += w5*v5.z; A0.w += w5*v5.w;
            A0.x += w6*v6.x; A0.y += w6*v6.y; A0.z += w6*v6.z; A0.w += w6*v6.w;
            A0.x += w7*v7.x; A0.y += w7*v7.y; A0.z += w7*v7.z; A0.w += w7*v7.w;
        }
        for (; e < cnt; ++e){
            int j = sbuf[e];
            float4 v = *reinterpret_cast<const float4*>(&hfeat[(size_t)j*512 + c0]);
            float w = wbuf[e][hr];
            A0.x += w*v.x; A0.y += w*v.y; A0.z += w*v.z; A0.w += w*v.w;
        }
        __syncthreads();
    }
    // reduce normalizer across lanes (each edge's weight was added by one lane)
    #pragma unroll
    for (int off = 1; off < 64; off <<= 1){
        #pragma unroll
        for (int h = 0; h < 4; ++h) sacc[h] += __shfl_xor(sacc[h], off);
    }
    // self loop + finalize (elu)
    float x = al_i[hr] + ar_i[hr];
    x = x >= 0.f ? x : 0.2f * x;
    float ws = __expf(x - mh[hr]);
    float4 hv = *reinterpret_cast<const float4*>(&hfeat[(size_t)i*512 + c0]);
    A0.x += ws*hv.x; A0.y += ws*hv.y; A0.z += ws*hv.z; A0.w += ws*hv.w;
    float inv = 1.f / (sacc[hr] + ws);
    float4 bv = *reinterpret_cast<const float4*>(&bias[c0]);
    float4 o;
    o.x = A0.x*inv + bv.x; o.y = A0.y*inv + bv.y;
    o.z = A0.z*inv + bv.z; o.w = A0.w*inv + bv.w;
    o.x = o.x > 0.f ? o.x : __expf(o.x) - 1.f;
    o.y = o.y > 0.f ? o.y : __expf(o.y) - 1.f;
    o.z = o.z > 0.f ? o.z : __expf(o.z) - 1.f;
    o.w = o.w > 0.f ? o.w : __expf(o.w) - 1.f;
    *reinterpret_cast<float4*>(&out[(size_t)g*512 + c0]) = o;
}

// ---------------------------------------------------------------- GAT2 agg, single-pass (global-bound m)
__global__ __launch_bounds__(64)
void gat_agg1_kernel(const float* __restrict__ hfeat,
                     const float* __restrict__ al, const float* __restrict__ ar,
                     const float* __restrict__ M1,
                     const int* __restrict__ rpA, const int* __restrict__ rpB, const int* __restrict__ rpC,
                     const int* __restrict__ clA, const int* __restrict__ clB, const int* __restrict__ clC,
                     const float* __restrict__ bias, float* __restrict__ out){
    const int bid = blockIdx.x;
    const int set = bid >> 12, i = bid & (NN - 1);
    const int tid = threadIdx.x;
    const int* rowptr = set == 0 ? rpA : set == 1 ? rpB : rpC;
    const int* cols   = set == 0 ? clA : set == 1 ? clB : clC;
    const int base = set * NN;
    const int start = rowptr[i], end = rowptr[i+1];
    const int deg = end - start;

    const float al_i = al[(size_t)base + i];
    const float ar_i = ar[(size_t)base + i];
    float mt = M1[0] + ar_i;
    const float m = mt >= 0.f ? mt : 0.2f * mt;

    __shared__ int   sbuf[64];
    __shared__ float wbv[64];
    float p0 = 0.f, p1 = 0.f, p2 = 0.f, p3 = 0.f;
    float sacc = 0.f;
    for (int k0 = 0; k0 < deg; k0 += 64){
        int cnt = min(64, deg - k0);
        if (tid < cnt){
            int j = cols[start + k0 + tid];
            sbuf[tid] = j;
            float x = al[(size_t)base + j] + ar_i;
            x = x >= 0.f ? x : 0.2f * x;
            float w = __expf(x - m);
            wbv[tid] = w;
            sacc += w;
        }
        __syncthreads();
        int e = 0;
        for (; e + 8 <= cnt; e += 8){
            int j0 = sbuf[e],   j1 = sbuf[e+1], j2 = sbuf[e+2], j3 = sbuf[e+3];
            int j4 = sbuf[e+4], j5 = sbuf[e+5], j6 = sbuf[e+6], j7 = sbuf[e+7];
            float v0 = hfeat[(size_t)(base + j0)*64 + tid];
            float v1 = hfeat[(size_t)(base + j1)*64 + tid];
            float v2 = hfeat[(size_t)(base + j2)*64 + tid];
            float v3 = hfeat[(size_t)(base + j3)*64 + tid];
            float v4 = hfeat[(size_t)(base + j4)*64 + tid];
            float v5 = hfeat[(size_t)(base + j5)*64 + tid];
            float v6 = hfeat[(size_t)(base + j6)*64 + tid];
            float v7 = hfeat[(size_t)(base + j7)*64 + tid];
            p0 += wbv[e  ] * v0; p1 += wbv[e+1] * v1;
            p2 += wbv[e+2] * v2; p3 += wbv[e+3] * v3;
            p0 += wbv[e+4] * v4; p1 += wbv[e+5] * v5;
            p2 += wbv[e+6] * v6; p3 += wbv[e+7] * v7;
        }
        for (; e < cnt; ++e)
            p0 += wbv[e] * hfeat[(size_t)(base + sbuf[e])*64 + tid];
        __syncthreads();
    }
    #pragma unroll
    for (int off = 1; off < 64; off <<= 1) sacc += __shfl_xor(sacc, off);
    float acc = (p0 + p1) + (p2 + p3);
    float x = al_i + ar_i;
    x = x >= 0.f ? x : 0.2f * x;
    float ws = __expf(x - m);
    acc += ws * hfeat[(size_t)(base + i)*64 + tid];
    float v = acc / (sacc + ws) + bias[tid];
    out[(size_t)bid*64 + tid] = fmaxf(v, 0.f);
}

// ---------------------------------------------------------------- GCN agg (+bias+relu), 2-set batched
template<int DIM>
__global__ __launch_bounds__(DIM)
void gcn_agg_kernel(const float* __restrict__ h,
                    const int* __restrict__ rpA, const int* __restrict__ rpB,
                    const int* __restrict__ clA, const int* __restrict__ clB,
                    const float* __restrict__ dvA, const float* __restrict__ dvB,
                    const float* __restrict__ bias, float* __restrict__ out){
    const int bid = blockIdx.x;
    const int set = bid >> 12, i = bid & (NN - 1);
    const int* rowptr = set ? rpB : rpA;
    const int* cols   = set ? clB : clA;
    const float* dinv = set ? dvB : dvA;
    const int c = threadIdx.x;
    const int start = rowptr[i], end = rowptr[i+1];
    const float di = dinv[i];
    const size_t rbase = (size_t)(set * NN) * DIM;
    float self = di * di * h[(size_t)bid * DIM + c];
    float p0 = 0.f, p1 = 0.f, p2 = 0.f, p3 = 0.f;
    int k = start;
    for (; k + 8 <= end; k += 8){
        int j0 = cols[k],   j1 = cols[k+1], j2 = cols[k+2], j3 = cols[k+3];
        int j4 = cols[k+4], j5 = cols[k+5], j6 = cols[k+6], j7 = cols[k+7];
        float v0 = h[rbase + (size_t)j0 * DIM + c];
        float v1 = h[rbase + (size_t)j1 * DIM + c];
        float v2 = h[rbase + (size_t)j2 * DIM + c];
        float v3 = h[rbase + (size_t)j3 * DIM + c];
        float v4 = h[rbase + (size_t)j4 * DIM + c];
        float v5 = h[rbase + (size_t)j5 * DIM + c];
        float v6 = h[rbase + (size_t)j6 * DIM + c];
        float v7 = h[rbase + (size_t)j7 * DIM + c];
        p0 += dinv[j0] * v0; p1 += dinv[j1] * v1;
        p2 += dinv[j2] * v2; p3 += dinv[j3] * v3;
        p0 += dinv[j4] * v4; p1 += dinv[j5] * v5;
        p2 += dinv[j6] * v6; p3 += dinv[j7] * v7;
    }
    for (; k < end; ++k){
        int j = cols[k];
        p0 += dinv[j] * h[rbase + (size_t)j * DIM + c];
    }
    float acc = self + di * ((p0 + p1) + (p2 + p3));
    out[(size_t)bid * DIM + c] = fmaxf(acc + bias[c], 0.f);
}

// ---------------------------------------------------------------- fused gate + GRU
__global__ __launch_bounds__(256)
void gate_gru_kernel(const float* __restrict__ h3, const float* __restrict__ h5,
                     const float* __restrict__ h6,
                     const float* __restrict__ A_W, const float* __restrict__ A_b,
                     const float* __restrict__ B_W, const float* __restrict__ B_b,
                     const float* __restrict__ Wih, const float* __restrict__ bih,
                     const float* __restrict__ Whh, const float* __restrict__ bhh,
                     float* __restrict__ cc){
    __shared__ float l3[4][256];
    __shared__ float l5[4][128];
    __shared__ float l6[4][64];
    __shared__ float lhg[4][64];
    const int lane = threadIdx.x & 63, wid = threadIdx.x >> 6;
    const int r = blockIdx.x * 4 + wid;
    for (int c = lane; c < 256; c += 64) l3[wid][c] = h3[(size_t)r*256 + c];
    for (int c = lane; c < 128; c += 64) l5[wid][c] = h5[(size_t)r*128 + c];
    l6[wid][lane] = h6[(size_t)r*64 + lane];
    WB();
    float a = A_b[lane];
    #pragma unroll 8
    for (int k = 0; k < 256; ++k) a += l3[wid][k] * A_W[k*64 + lane];
    float b = B_b[lane];
    #pragma unroll 8
    for (int k = 0; k < 128; ++k) b += l5[wid][k] * B_W[k*64 + lane];
    float z = 1.f / (1.f + expf(-(a + b)));
    float hg = z * b + (1.f - z) * a;
    lhg[wid][lane] = hg;
    WB();
    float gi0 = bih[lane], gi1 = bih[64 + lane], gi2 = bih[128 + lane];
    float gh0 = bhh[lane], gh1 = bhh[64 + lane], gh2 = bhh[128 + lane];
    #pragma unroll 4
    for (int k = 0; k < 64; ++k){
        float v6 = l6[wid][k], vh = lhg[wid][k];
        gi0 += v6 * Wih[k*192 + lane];
        gi1 += v6 * Wih[k*192 + 64 + lane];
        gi2 += v6 * Wih[k*192 + 128 + lane];
        gh0 += vh * Whh[k*192 + lane];
        gh1 += vh * Whh[k*192 + 64 + lane];
        gh2 += vh * Whh[k*192 + 128 + lane];
    }
    float rr = 1.f / (1.f + expf(-(gi0 + gh0)));
    float zz = 1.f / (1.f + expf(-(gi1 + gh1)));
    float nn = tanhf(gi2 + rr * gh2);
    cc[(size_t)r*64 + lane] = (1.f - zz) * nn + zz * hg;
}

// ---------------------------------------------------------------- fused head (pool -> f1 -> f2)
__global__ __launch_bounds__(256)
void head_kernel(const float* __restrict__ cc,
                 const float* __restrict__ f1_W, const float* __restrict__ f1_b,
                 const float* __restrict__ f2_W, const float* __restrict__ f2_b,
                 float* __restrict__ out){
    const int b = blockIdx.x, tid = threadIdx.x;
    const int c = tid & 63, grp = tid >> 6;
    __shared__ float red4[4][64];
    __shared__ float gmax[64];
    __shared__ float fgs[128];
    const float* base = cc + (size_t)(b * (NN / NG)) * 64;
    float m = -1e30f;
    #pragma unroll 8
    for (int n = grp; n < NN / NG; n += 4) m = fmaxf(m, base[n * 64 + c]);
    red4[grp][c] = m;
    __syncthreads();
    if (tid < 64)
        gmax[tid] = fmaxf(fmaxf(red4[0][tid], red4[1][tid]),
                          fmaxf(red4[2][tid], red4[3][tid]));
    __syncthreads();
    if (tid < 128){
        float acc = 0.f;
        #pragma unroll
        for (int k = 0; k < 64; ++k) acc += gmax[k] * f1_W[k * 128 + tid];
        fgs[tid] = fmaxf(acc + f1_b[tid], 0.f);
    }
    __syncthreads();
    if (tid < 120){
        float acc = 0.f;
        #pragma unroll
        for (int k = 0; k < 128; ++k) acc += fgs[k] * f2_W[k * 120 + tid];
        out[b * 120 + tid] = acc + f2_b[tid];
    }
}

// ---------------------------------------------------------------- driver
extern "C" void kernel_launch(void* const* d_in, const int* in_sizes, int n_in,
                              void* d_out, int out_size, void* d_ws, size_t ws_size,
                              hipStream_t stream){
    const float* x  = (const float*)d_in[0];
    const int* e1 = (const int*)d_in[1]; const int E1 = in_sizes[1] / 2;
    const int* e2 = (const int*)d_in[2]; const int E2 = in_sizes[2] / 2;
    const int* e3 = (const int*)d_in[3]; const int E3 = in_sizes[3] / 2;
    const float* g1_W  = (const float*)d_in[5];
    const float* g1_as = (const float*)d_in[6];
    const float* g1_ad = (const float*)d_in[7];
    const float* g1_b  = (const float*)d_in[8];
    const float* g2_W  = (const float*)d_in[9];
    const float* g2_as = (const float*)d_in[10];
    const float* g2_ad = (const float*)d_in[11];
    const float* g2_b  = (const float*)d_in[12];
    const float* gfc_W = (const float*)d_in[13];
    const float* gfc_b = (const float*)d_in[14];
    const float* gfc1_W= (const float*)d_in[15];
    const float* gfc1_b= (const float*)d_in[16];
    const float* gout_W= (const float*)d_in[17];
    const float* gout_b= (const float*)d_in[18];
    const float* c2_W  = (const float*)d_in[19];
    const float* c2_b  = (const float*)d_in[20];
    const float* c3_W  = (const float*)d_in[21];
    const float* c3_b  = (const float*)d_in[22];
    const float* A_W   = (const float*)d_in[23];
    const float* A_b   = (const float*)d_in[24];
    const float* B_W   = (const float*)d_in[25];
    const float* B_b   = (const float*)d_in[26];
    const float* Wih   = (const float*)d_in[27];
    const float* Whh   = (const float*)d_in[28];
    const float* bih   = (const float*)d_in[29];
    const float* bhh   = (const float*)d_in[30];
    const float* f1_W  = (const float*)d_in[31];
    const float* f1_b  = (const float*)d_in[32];
    const float* f2_W  = (const float*)d_in[33];
    const float* f2_b  = (const float*)d_in[34];
    float* out = (float*)d_out;

    // ---- workspace layout (~38 MB)
    int* ip = (int*)d_ws;
    int* rp1 = ip; int* rp2 = ip + 4100; int* rp3 = ip + 8200;
    float* fb = (float*)(ip + 12300);
    size_t o = 0;
    auto alloc = [&](size_t nf){ float* p = fb + o; o += nf; return p; };
    float* dinv1 = alloc(NN);
    float* dinv2 = alloc(NN);
    float* M8buf = alloc(8);
    float* M1buf = alloc(8);
    float* hbuf  = alloc((size_t)NN*512);       // x@g1_W [4096,512]; later houts [12288,64]
    float* al1   = alloc((size_t)NN*8);
    float* ar1   = alloc((size_t)NN*8);
    float* bigA  = alloc((size_t)3*NN*512);     // eluo3 [12288,512]; later sliced
    float* t2    = alloc((size_t)3*NN*64);      // GAT2 features [12288,64]
    float* al2   = alloc((size_t)3*NN);
    float* ar2   = alloc((size_t)3*NN);
    (void)ws_size; (void)n_in; (void)out_size;

    float* eluo3 = bigA;                        // [12288,512]
    float* g2o   = bigA;                        // [12288,64]
    float* fc1   = bigA + (size_t)786432;       // [12288,64]
    float* fc2   = bigA + (size_t)1572864;      // [12288,128]
    float* houts = hbuf;                        // [12288,64]  (hbuf dead)
    float* h1    = houts;                       // rows 0-4095
    float* h6    = houts + (size_t)2*NN*64;     // rows 8192-12287
    float* gcnx2 = bigA + (size_t)3145728;      // [8192,128]
    float* h25   = bigA + (size_t)4194304;      // [8192,128] = h2 ; h5
    float* h2    = h25;
    float* h5    = h25 + (size_t)NN*128;
    float* gcnx3 = bigA;                        // [4096,256] (g2o/fc1 dead)
    float* h3    = bigA + (size_t)1048576;      // [4096,256] (fc2 dead)
    float* ccb   = bigA + (size_t)4456448;      // [4096,64]
    const int* cols1 = e1 + E1; const int* cols2 = e2 + E2; const int* cols3 = e3 + E3;

    // ---- CSR + dinv
    rowptr3_kernel<<<(3*(NN+1)+255)/256, 256, 0, stream>>>(e1, E1, e2, E2, e3, E3, rp1, rp2, rp3);
    dinv2_kernel<<<2*NN/256, 256, 0, stream>>>(rp1, rp2, dinv1, dinv2);

    // ---- GAT pipeline (attention dots fused into the producing GEMMs; single-pass softmax)
    gemm_attn8_kernel<<<dim3(8, 64), 256, 0, stream>>>(x, g1_W, hbuf, g1_as, g1_ad, al1, ar1);
    max_al_kernel<8><<<1, 256, 0, stream>>>(al1, NN, M8buf);
    gat_agg8_p2_kernel<<<6*NN, 64, 0, stream>>>(hbuf, al1, ar1, M8buf,
        rp1, rp2, rp3, cols1, cols2, cols3, g1_b, eluo3);
    gemm32_attn1_kernel<<<dim3(1, 384), 256, 0, stream>>>(eluo3, g2_W, t2, g2_as, g2_ad, al2, ar2);
    max_al_kernel<1><<<1, 256, 0, stream>>>(al2, 3*NN, M1buf);
    gat_agg1_kernel<<<3*NN, 64, 0, stream>>>(t2, al2, ar2, M1buf,
        rp1, rp2, rp3, cols1, cols2, cols3, g2_b, g2o);
    gemm32_kernel<<<dim3(1, 384), 256, 0, stream>>>(g2o, gfc_W, gfc_b, fc1, 64, 64, 1);
    gemm_kernel<<<dim3(2, 192), 256, 0, stream>>>(fc1, gfc1_W, gfc1_b, fc2, 64, 128, 1);
    gemm32_kernel<<<dim3(1, 384), 256, 0, stream>>>(fc2, gout_W, gout_b, houts, 128, 64, 1);

    // ---- GCN chain
    gemm_kernel<<<dim3(2, 128), 256, 0, stream>>>(houts, c2_W, nullptr, gcnx2, 64, 128, 0);
    gcn_agg_kernel<128><<<2*NN, 128, 0, stream>>>(gcnx2, rp1, rp2, cols1, cols2,
                                                  dinv1, dinv2, c2_b, h25);
    gemm_kernel<<<dim3(4, 64), 256, 0, stream>>>(h2, c3_W, nullptr, gcnx3, 128, 256, 0);
    gcn_agg_kernel<256><<<NN, 256, 0, stream>>>(gcnx3, rp1, rp1, cols1, cols1,
                                                dinv1, dinv1, c3_b, h3);

    // ---- fused gate + GRU
    gate_gru_kernel<<<NN/4, 256, 0, stream>>>(h3, h5, h6, A_W, A_b, B_W, B_b,
                                              Wih, bih, Whh, bhh, ccb);

    // ---- fused pool + f1 + f2
    head_kernel<<<NG, 256, 0, stream>>>(ccb, f1_W, f1_b, f2_W, f2_b, out);
}

// Round 16
// 347.710 us; speedup vs baseline: 1.0311x; 1.0311x over previous
//
#include <hip/hip_runtime.h>
#include <math.h>

#define NN 4096      // nodes
#define NG 16        // graphs
#define WB() __builtin_amdgcn_wave_barrier()

// order-preserving float<->uint bijection (for exact atomic max over floats)
__device__ __forceinline__ unsigned enc_f(float x){
    unsigned u = __float_as_uint(x);
    return (u & 0x80000000u) ? ~u : (u | 0x80000000u);
}
__device__ __forceinline__ float dec_f(unsigned e){
    return (e & 0x80000000u) ? __uint_as_float(e ^ 0x80000000u) : __uint_as_float(~e);
}

// ---------------------------------------------------------------- CSR prep
__global__ void rowptr3_kernel(const int* __restrict__ ea, int Ea,
                               const int* __restrict__ eb, int Eb,
                               const int* __restrict__ ec, int Ec,
                               int* __restrict__ rpa, int* __restrict__ rpb, int* __restrict__ rpc){
    int t = blockIdx.x * blockDim.x + threadIdx.x;
    int set = t / (NN + 1), i = t % (NN + 1);
    if (set >= 3) return;
    const int* e0 = set == 0 ? ea : set == 1 ? eb : ec;
    int E        = set == 0 ? Ea : set == 1 ? Eb : Ec;
    int* rp      = set == 0 ? rpa : set == 1 ? rpb : rpc;
    if (i == NN){ rp[NN] = E; return; }
    int lo = 0, hi = E;
    while (lo < hi){ int mid = (lo + hi) >> 1; if (e0[mid] < i) lo = mid + 1; else hi = mid; }
    rp[i] = lo;
}

// dinv + init of the 9 encoded-max cells (runs first every launch; ws re-poisoned)
__global__ void dinv2_kernel(const int* __restrict__ rp1, const int* __restrict__ rp2,
                             float* __restrict__ dinv1, float* __restrict__ dinv2,
                             unsigned* __restrict__ Menc){
    int t = blockIdx.x * blockDim.x + threadIdx.x;
    if (t < 9) Menc[t] = enc_f(-1e30f);
    int set = t >> 12, i = t & (NN - 1);
    if (set >= 2) return;
    const int* rp = set ? rp2 : rp1;
    float deg = (float)(rp[i+1] - rp[i] + 1);          // +1 self loop
    (set ? dinv2 : dinv1)[i] = 1.0f / sqrtf(deg);
}

// ---------------------------------------------------------------- dense GEMM (64-row tile)
__global__ __launch_bounds__(256)
void gemm_kernel(const float* __restrict__ A, const float* __restrict__ W,
                 const float* __restrict__ bias, float* __restrict__ C,
                 int K, int Nc, int act){
    __shared__ float As[64][17];
    __shared__ float Bs[16][64];
    const int tid = threadIdx.x;
    const int tx = tid & 15, ty = tid >> 4;
    const int row0 = blockIdx.y * 64, col0 = blockIdx.x * 64;
    float acc[4][4] = {};
    for (int k0 = 0; k0 < K; k0 += 16){
        {   int idx = tid * 4; int r = idx >> 4, kk = idx & 15;
            float4 av = *reinterpret_cast<const float4*>(&A[(size_t)(row0 + r) * K + k0 + kk]);
            As[r][kk+0]=av.x; As[r][kk+1]=av.y; As[r][kk+2]=av.z; As[r][kk+3]=av.w; }
        {   int idx = tid * 4; int r = idx >> 6, cc = idx & 63;
            float4 wv = *reinterpret_cast<const float4*>(&W[(size_t)(k0 + r) * Nc + col0 + cc]);
            *reinterpret_cast<float4*>(&Bs[r][cc]) = wv; }
        __syncthreads();
        #pragma unroll
        for (int kk = 0; kk < 16; ++kk){
            float a[4], b[4];
            #pragma unroll
            for (int i = 0; i < 4; ++i) a[i] = As[ty*4+i][kk];
            #pragma unroll
            for (int j = 0; j < 4; ++j) b[j] = Bs[kk][tx*4+j];
            #pragma unroll
            for (int i = 0; i < 4; ++i)
                #pragma unroll
                for (int j = 0; j < 4; ++j) acc[i][j] += a[i]*b[j];
        }
        __syncthreads();
    }
    #pragma unroll
    for (int i = 0; i < 4; ++i){
        int r = row0 + ty*4 + i;
        #pragma unroll
        for (int j = 0; j < 4; ++j){
            int c = col0 + tx*4 + j;
            float v = acc[i][j] + (bias ? bias[c] : 0.0f);
            if (act == 1) v = fmaxf(v, 0.0f);
            C[(size_t)r * Nc + c] = v;
        }
    }
}

// GEMM (64-row tile, Nc=512) + fused 8-head attention dots + global al-max (atomic)
__global__ __launch_bounds__(256)
void gemm_attn8_kernel(const float* __restrict__ A, const float* __restrict__ W,
                       float* __restrict__ C,
                       const float* __restrict__ a_src, const float* __restrict__ a_dst,
                       float* __restrict__ al, float* __restrict__ ar,
                       unsigned* __restrict__ Menc){
    __shared__ float As[64][17];
    __shared__ float Bs[16][64];
    __shared__ float redal[64][17];
    __shared__ float redar[64][17];
    const int tid = threadIdx.x;
    const int tx = tid & 15, ty = tid >> 4;
    const int row0 = blockIdx.y * 64, col0 = blockIdx.x * 64;
    const int K = 64, Nc = 512;
    float acc[4][4] = {};
    for (int k0 = 0; k0 < K; k0 += 16){
        {   int idx = tid * 4; int r = idx >> 4, kk = idx & 15;
            float4 av = *reinterpret_cast<const float4*>(&A[(size_t)(row0 + r) * K + k0 + kk]);
            As[r][kk+0]=av.x; As[r][kk+1]=av.y; As[r][kk+2]=av.z; As[r][kk+3]=av.w; }
        {   int idx = tid * 4; int r = idx >> 6, cc = idx & 63;
            float4 wv = *reinterpret_cast<const float4*>(&W[(size_t)(k0 + r) * Nc + col0 + cc]);
            *reinterpret_cast<float4*>(&Bs[r][cc]) = wv; }
        __syncthreads();
        #pragma unroll
        for (int kk = 0; kk < 16; ++kk){
            float a[4], b[4];
            #pragma unroll
            for (int i = 0; i < 4; ++i) a[i] = As[ty*4+i][kk];
            #pragma unroll
            for (int j = 0; j < 4; ++j) b[j] = Bs[kk][tx*4+j];
            #pragma unroll
            for (int i = 0; i < 4; ++i)
                #pragma unroll
                for (int j = 0; j < 4; ++j) acc[i][j] += a[i]*b[j];
        }
        __syncthreads();
    }
    float pal[4] = {0.f,0.f,0.f,0.f}, par[4] = {0.f,0.f,0.f,0.f};
    #pragma unroll
    for (int j = 0; j < 4; ++j){
        int c = col0 + tx*4 + j;
        float as = a_src[c], ad = a_dst[c];
        #pragma unroll
        for (int i = 0; i < 4; ++i){
            pal[i] += acc[i][j] * as;
            par[i] += acc[i][j] * ad;
        }
    }
    #pragma unroll
    for (int i = 0; i < 4; ++i){
        int r = row0 + ty*4 + i;
        #pragma unroll
        for (int j = 0; j < 4; ++j)
            C[(size_t)r * Nc + col0 + tx*4 + j] = acc[i][j];
        redal[ty*4+i][tx] = pal[i];
        redar[ty*4+i][tx] = par[i];
    }
    __syncthreads();
    if (tid < 64){
        float sa = 0.f, sr = 0.f;
        #pragma unroll
        for (int t = 0; t < 16; ++t){ sa += redal[tid][t]; sr += redar[tid][t]; }
        al[(size_t)(row0 + tid)*8 + blockIdx.x] = sa;
        ar[(size_t)(row0 + tid)*8 + blockIdx.x] = sr;
        float mx = sa;
        #pragma unroll
        for (int off = 1; off < 64; off <<= 1) mx = fmaxf(mx, __shfl_xor(mx, off));
        if (tid == 0) atomicMax(&Menc[blockIdx.x], enc_f(mx));
    }
}

// 32-row tile variant for narrow GEMMs
__global__ __launch_bounds__(256)
void gemm32_kernel(const float* __restrict__ A, const float* __restrict__ W,
                   const float* __restrict__ bias, float* __restrict__ C,
                   int K, int Nc, int act){
    __shared__ float As[32][17];
    __shared__ float Bs[16][64];
    const int tid = threadIdx.x;
    const int tx = tid & 15, ty = tid >> 4;
    const int row0 = blockIdx.y * 32, col0 = blockIdx.x * 64;
    float acc[2][4] = {};
    for (int k0 = 0; k0 < K; k0 += 16){
        {   int idx = tid * 2; int r = idx >> 4, kk = idx & 15;
            float2 av = *reinterpret_cast<const float2*>(&A[(size_t)(row0 + r) * K + k0 + kk]);
            As[r][kk] = av.x; As[r][kk+1] = av.y; }
        {   int idx = tid * 4; int r = idx >> 6, cc = idx & 63;
            *reinterpret_cast<float4*>(&Bs[r][cc]) =
                *reinterpret_cast<const float4*>(&W[(size_t)(k0 + r) * Nc + col0 + cc]); }
        __syncthreads();
        #pragma unroll
        for (int kk = 0; kk < 16; ++kk){
            float a0 = As[ty*2][kk], a1 = As[ty*2+1][kk];
            float b[4];
            #pragma unroll
            for (int j = 0; j < 4; ++j) b[j] = Bs[kk][tx*4+j];
            #pragma unroll
            for (int j = 0; j < 4; ++j){ acc[0][j] += a0*b[j]; acc[1][j] += a1*b[j]; }
        }
        __syncthreads();
    }
    #pragma unroll
    for (int i = 0; i < 2; ++i){
        int r = row0 + ty*2 + i;
        #pragma unroll
        for (int j = 0; j < 4; ++j){
            int c = col0 + tx*4 + j;
            float v = acc[i][j] + (bias ? bias[c] : 0.0f);
            if (act == 1) v = fmaxf(v, 0.0f);
            C[(size_t)r * Nc + c] = v;
        }
    }
}

// 32-row GEMM (K=512, Nc=64) + fused 1-head attention dots + global al-max (atomic)
__global__ __launch_bounds__(256)
void gemm32_attn1_kernel(const float* __restrict__ A, const float* __restrict__ W,
                         float* __restrict__ C,
                         const float* __restrict__ a_src, const float* __restrict__ a_dst,
                         float* __restrict__ al, float* __restrict__ ar,
                         unsigned* __restrict__ Menc){
    __shared__ float As[32][17];
    __shared__ float Bs[16][64];
    __shared__ float redal[32][17];
    __shared__ float redar[32][17];
    const int tid = threadIdx.x;
    const int tx = tid & 15, ty = tid >> 4;
    const int row0 = blockIdx.y * 32;
    const int K = 512, Nc = 64;
    float acc[2][4] = {};
    for (int k0 = 0; k0 < K; k0 += 16){
        {   int idx = tid * 2; int r = idx >> 4, kk = idx & 15;
            float2 av = *reinterpret_cast<const float2*>(&A[(size_t)(row0 + r) * K + k0 + kk]);
            As[r][kk] = av.x; As[r][kk+1] = av.y; }
        {   int idx = tid * 4; int r = idx >> 6, cc = idx & 63;
            *reinterpret_cast<float4*>(&Bs[r][cc]) =
                *reinterpret_cast<const float4*>(&W[(size_t)(k0 + r) * Nc + cc]); }
        __syncthreads();
        #pragma unroll
        for (int kk = 0; kk < 16; ++kk){
            float a0 = As[ty*2][kk], a1 = As[ty*2+1][kk];
            float b[4];
            #pragma unroll
            for (int j = 0; j < 4; ++j) b[j] = Bs[kk][tx*4+j];
            #pragma unroll
            for (int j = 0; j < 4; ++j){ acc[0][j] += a0*b[j]; acc[1][j] += a1*b[j]; }
        }
        __syncthreads();
    }
    float pal[2] = {0.f,0.f}, par[2] = {0.f,0.f};
    #pragma unroll
    for (int j = 0; j < 4; ++j){
        int c = tx*4 + j;
        float as = a_src[c], ad = a_dst[c];
        pal[0] += acc[0][j]*as; pal[1] += acc[1][j]*as;
        par[0] += acc[0][j]*ad; par[1] += acc[1][j]*ad;
    }
    #pragma unroll
    for (int i = 0; i < 2; ++i){
        int r = row0 + ty*2 + i;
        #pragma unroll
        for (int j = 0; j < 4; ++j)
            C[(size_t)r * Nc + tx*4 + j] = acc[i][j];
        redal[ty*2+i][tx] = pal[i];
        redar[ty*2+i][tx] = par[i];
    }
    __syncthreads();
    if (tid < 32){
        float sa = 0.f, sr = 0.f;
        #pragma unroll
        for (int t = 0; t < 16; ++t){ sa += redal[tid][t]; sr += redar[tid][t]; }
        al[row0 + tid] = sa;
        ar[row0 + tid] = sr;
        float mx = sa;
        #pragma unroll
        for (int off = 1; off < 32; off <<= 1) mx = fmaxf(mx, __shfl_xor(mx, off));
        if (tid == 0) atomicMax(&Menc[8], enc_f(mx));
    }
}

// ---------------------------------------------------------------- GAT1 agg, channel-split, single-pass
// m = leaky_relu(M[h] + ar_i) (global-bound stabilizer, softmax-invariant);
// normalizer s accumulated in the gather pass (each edge counted once).
__global__ __launch_bounds__(64)
void gat_agg8_p2_kernel(const float* __restrict__ hfeat,
                        const float* __restrict__ al, const float* __restrict__ ar,
                        const unsigned* __restrict__ Menc,
                        const int* __restrict__ rpA, const int* __restrict__ rpB, const int* __restrict__ rpC,
                        const int* __restrict__ clA, const int* __restrict__ clB, const int* __restrict__ clC,
                        const float* __restrict__ bias, float* __restrict__ out){
    const int bid = blockIdx.x;
    const int g = bid >> 1, half = bid & 1;
    const int set = g >> 12, i = g & (NN - 1);
    const int lane = threadIdx.x;
    const int* rowptr = set == 0 ? rpA : set == 1 ? rpB : rpC;
    const int* cols   = set == 0 ? clA : set == 1 ? clB : clC;
    const int start = rowptr[i], end = rowptr[i+1];
    const int deg = end - start;
    const int hb = half * 4;
    const int c0 = half * 256 + 4 * lane;
    const int hr = lane >> 4;

    float4 arv = *reinterpret_cast<const float4*>(&ar[(size_t)i*8 + hb]);
    float ar_i[4] = {arv.x, arv.y, arv.z, arv.w};
    float4 alv = *reinterpret_cast<const float4*>(&al[(size_t)i*8 + hb]);
    float al_i[4] = {alv.x, alv.y, alv.z, alv.w};
    float mh[4];
    #pragma unroll
    for (int h = 0; h < 4; ++h){
        float t = dec_f(Menc[hb + h]) + ar_i[h];
        mh[h] = t >= 0.f ? t : 0.2f * t;      // lr monotone => >= all neighborhood logits
    }

    __shared__ int   sbuf[64];
    __shared__ float wbuf[64][5];
    float4 A0 = {0.f, 0.f, 0.f, 0.f};
    float sacc[4] = {0.f, 0.f, 0.f, 0.f};
    for (int k0 = 0; k0 < deg; k0 += 64){
        int cnt = min(64, deg - k0);
        if (lane < cnt){
            int j = cols[start + k0 + lane];
            sbuf[lane] = j;
            float4 av = *reinterpret_cast<const float4*>(&al[(size_t)j*8 + hb]);
            float a4[4] = {av.x, av.y, av.z, av.w};
            #pragma unroll
            for (int h = 0; h < 4; ++h){
                float x = a4[h] + ar_i[h];
                x = x >= 0.f ? x : 0.2f * x;
                float w = __expf(x - mh[h]);
                wbuf[lane][h] = w;
                sacc[h] += w;                  // this edge counted exactly once
            }
        }
        __syncthreads();
        int e = 0;
        for (; e + 8 <= cnt; e += 8){
            int j0 = sbuf[e],   j1 = sbuf[e+1], j2 = sbuf[e+2], j3 = sbuf[e+3];
            int j4 = sbuf[e+4], j5 = sbuf[e+5], j6 = sbuf[e+6], j7 = sbuf[e+7];
            float4 v0 = *reinterpret_cast<const float4*>(&hfeat[(size_t)j0*512 + c0]);
            float4 v1 = *reinterpret_cast<const float4*>(&hfeat[(size_t)j1*512 + c0]);
            float4 v2 = *reinterpret_cast<const float4*>(&hfeat[(size_t)j2*512 + c0]);
            float4 v3 = *reinterpret_cast<const float4*>(&hfeat[(size_t)j3*512 + c0]);
            float4 v4 = *reinterpret_cast<const float4*>(&hfeat[(size_t)j4*512 + c0]);
            float4 v5 = *reinterpret_cast<const float4*>(&hfeat[(size_t)j5*512 + c0]);
            float4 v6 = *reinterpret_cast<const float4*>(&hfeat[(size_t)j6*512 + c0]);
            float4 v7 = *reinterpret_cast<const float4*>(&hfeat[(size_t)j7*512 + c0]);
            float w0 = wbuf[e  ][hr], w1 = wbuf[e+1][hr], w2 = wbuf[e+2][hr], w3 = wbuf[e+3][hr];
            float w4 = wbuf[e+4][hr], w5 = wbuf[e+5][hr], w6 = wbuf[e+6][hr], w7 = wbuf[e+7][hr];
            A0.x += w0*v0.x; A0.y += w0*v0.y; A0.z += w0*v0.z; A0.w += w0*v0.w;
            A0.x += w1*v1.x; A0.y += w1*v1.y; A0.z += w1*v1.z; A0.w += w1*v1.w;
            A0.x += w2*v2.x; A0.y += w2*v2.y; A0.z += w2*v2.z; A0.w += w2*v2.w;
            A0.x += w3*v3.x; A0.y += w3*v3.y; A0.z += w3*v3.z; A0.w += w3*v3.w;
            A0.x += w4*v4.x; A0.y += w4*v4.y; A0.z += w4*v4.z; A0.w += w4*v4.w;
            A0.x += w5*v5.x; A0.y += w5*v5.y; A0.z += w5*v5.z; A0.w += w5*v5.w;
            A0.x += w6*v6.x; A0.y += w6*v6.y; A0.z += w6*v6.z; A0.w += w6*v6.w;
            A0.x += w7*v7.x; A0.y += w7*v7.y; A0.z += w7*v7.z; A0.w += w7*v7.w;
        }
        for (; e < cnt; ++e){
            int j = sbuf[e];
            float4 v = *reinterpret_cast<const float4*>(&hfeat[(size_t)j*512 + c0]);
            float w = wbuf[e][hr];
            A0.x += w*v.x; A0.y += w*v.y; A0.z += w*v.z; A0.w += w*v.w;
        }
        __syncthreads();
    }
    #pragma unroll
    for (int off = 1; off < 64; off <<= 1){
        #pragma unroll
        for (int h = 0; h < 4; ++h) sacc[h] += __shfl_xor(sacc[h], off);
    }
    // self loop + finalize (elu)
    float x = al_i[hr] + ar_i[hr];
    x = x >= 0.f ? x : 0.2f * x;
    float ws = __expf(x - mh[hr]);
    float4 hv = *reinterpret_cast<const float4*>(&hfeat[(size_t)i*512 + c0]);
    A0.x += ws*hv.x; A0.y += ws*hv.y; A0.z += ws*hv.z; A0.w += ws*hv.w;
    float inv = 1.f / (sacc[hr] + ws);
    float4 bv = *reinterpret_cast<const float4*>(&bias[c0]);
    float4 o;
    o.x = A0.x*inv + bv.x; o.y = A0.y*inv + bv.y;
    o.z = A0.z*inv + bv.z; o.w = A0.w*inv + bv.w;
    o.x = o.x > 0.f ? o.x : __expf(o.x) - 1.f;
    o.y = o.y > 0.f ? o.y : __expf(o.y) - 1.f;
    o.z = o.z > 0.f ? o.z : __expf(o.z) - 1.f;
    o.w = o.w > 0.f ? o.w : __expf(o.w) - 1.f;
    *reinterpret_cast<float4*>(&out[(size_t)g*512 + c0]) = o;
}

// ---------------------------------------------------------------- GAT2 agg, single-pass (global-bound m)
__global__ __launch_bounds__(64)
void gat_agg1_kernel(const float* __restrict__ hfeat,
                     const float* __restrict__ al, const float* __restrict__ ar,
                     const unsigned* __restrict__ Menc,
                     const int* __restrict__ rpA, const int* __restrict__ rpB, const int* __restrict__ rpC,
                     const int* __restrict__ clA, const int* __restrict__ clB, const int* __restrict__ clC,
                     const float* __restrict__ bias, float* __restrict__ out){
    const int bid = blockIdx.x;
    const int set = bid >> 12, i = bid & (NN - 1);
    const int tid = threadIdx.x;
    const int* rowptr = set == 0 ? rpA : set == 1 ? rpB : rpC;
    const int* cols   = set == 0 ? clA : set == 1 ? clB : clC;
    const int base = set * NN;
    const int start = rowptr[i], end = rowptr[i+1];
    const int deg = end - start;

    const float al_i = al[(size_t)base + i];
    const float ar_i = ar[(size_t)base + i];
    float mt = dec_f(Menc[8]) + ar_i;
    const float m = mt >= 0.f ? mt : 0.2f * mt;

    __shared__ int   sbuf[64];
    __shared__ float wbv[64];
    float p0 = 0.f, p1 = 0.f, p2 = 0.f, p3 = 0.f;
    float sacc = 0.f;
    for (int k0 = 0; k0 < deg; k0 += 64){
        int cnt = min(64, deg - k0);
        if (tid < cnt){
            int j = cols[start + k0 + tid];
            sbuf[tid] = j;
            float x = al[(size_t)base + j] + ar_i;
            x = x >= 0.f ? x : 0.2f * x;
            float w = __expf(x - m);
            wbv[tid] = w;
            sacc += w;
        }
        __syncthreads();
        int e = 0;
        for (; e + 8 <= cnt; e += 8){
            int j0 = sbuf[e],   j1 = sbuf[e+1], j2 = sbuf[e+2], j3 = sbuf[e+3];
            int j4 = sbuf[e+4], j5 = sbuf[e+5], j6 = sbuf[e+6], j7 = sbuf[e+7];
            float v0 = hfeat[(size_t)(base + j0)*64 + tid];
            float v1 = hfeat[(size_t)(base + j1)*64 + tid];
            float v2 = hfeat[(size_t)(base + j2)*64 + tid];
            float v3 = hfeat[(size_t)(base + j3)*64 + tid];
            float v4 = hfeat[(size_t)(base + j4)*64 + tid];
            float v5 = hfeat[(size_t)(base + j5)*64 + tid];
            float v6 = hfeat[(size_t)(base + j6)*64 + tid];
            float v7 = hfeat[(size_t)(base + j7)*64 + tid];
            p0 += wbv[e  ] * v0; p1 += wbv[e+1] * v1;
            p2 += wbv[e+2] * v2; p3 += wbv[e+3] * v3;
            p0 += wbv[e+4] * v4; p1 += wbv[e+5] * v5;
            p2 += wbv[e+6] * v6; p3 += wbv[e+7] * v7;
        }
        for (; e < cnt; ++e)
            p0 += wbv[e] * hfeat[(size_t)(base + sbuf[e])*64 + tid];
        __syncthreads();
    }
    #pragma unroll
    for (int off = 1; off < 64; off <<= 1) sacc += __shfl_xor(sacc, off);
    float acc = (p0 + p1) + (p2 + p3);
    float x = al_i + ar_i;
    x = x >= 0.f ? x : 0.2f * x;
    float ws = __expf(x - m);
    acc += ws * hfeat[(size_t)(base + i)*64 + tid];
    float v = acc / (sacc + ws) + bias[tid];
    out[(size_t)bid*64 + tid] = fmaxf(v, 0.f);
}

// ---------------------------------------------------------------- GCN agg (+bias+relu), 2-set batched
template<int DIM>
__global__ __launch_bounds__(DIM)
void gcn_agg_kernel(const float* __restrict__ h,
                    const int* __restrict__ rpA, const int* __restrict__ rpB,
                    const int* __restrict__ clA, const int* __restrict__ clB,
                    const float* __restrict__ dvA, const float* __restrict__ dvB,
                    const float* __restrict__ bias, float* __restrict__ out){
    const int bid = blockIdx.x;
    const int set = bid >> 12, i = bid & (NN - 1);
    const int* rowptr = set ? rpB : rpA;
    const int* cols   = set ? clB : clA;
    const float* dinv = set ? dvB : dvA;
    const int c = threadIdx.x;
    const int start = rowptr[i], end = rowptr[i+1];
    const float di = dinv[i];
    const size_t rbase = (size_t)(set * NN) * DIM;
    float self = di * di * h[(size_t)bid * DIM + c];
    float p0 = 0.f, p1 = 0.f, p2 = 0.f, p3 = 0.f;
    int k = start;
    for (; k + 8 <= end; k += 8){
        int j0 = cols[k],   j1 = cols[k+1], j2 = cols[k+2], j3 = cols[k+3];
        int j4 = cols[k+4], j5 = cols[k+5], j6 = cols[k+6], j7 = cols[k+7];
        float v0 = h[rbase + (size_t)j0 * DIM + c];
        float v1 = h[rbase + (size_t)j1 * DIM + c];
        float v2 = h[rbase + (size_t)j2 * DIM + c];
        float v3 = h[rbase + (size_t)j3 * DIM + c];
        float v4 = h[rbase + (size_t)j4 * DIM + c];
        float v5 = h[rbase + (size_t)j5 * DIM + c];
        float v6 = h[rbase + (size_t)j6 * DIM + c];
        float v7 = h[rbase + (size_t)j7 * DIM + c];
        p0 += dinv[j0] * v0; p1 += dinv[j1] * v1;
        p2 += dinv[j2] * v2; p3 += dinv[j3] * v3;
        p0 += dinv[j4] * v4; p1 += dinv[j5] * v5;
        p2 += dinv[j6] * v6; p3 += dinv[j7] * v7;
    }
    for (; k < end; ++k){
        int j = cols[k];
        p0 += dinv[j] * h[rbase + (size_t)j * DIM + c];
    }
    float acc = self + di * ((p0 + p1) + (p2 + p3));
    out[(size_t)bid * DIM + c] = fmaxf(acc + bias[c], 0.f);
}

// ---------------------------------------------------------------- fused gate + GRU
__global__ __launch_bounds__(256)
void gate_gru_kernel(const float* __restrict__ h3, const float* __restrict__ h5,
                     const float* __restrict__ h6,
                     const float* __restrict__ A_W, const float* __restrict__ A_b,
                     const float* __restrict__ B_W, const float* __restrict__ B_b,
                     const float* __restrict__ Wih, const float* __restrict__ bih,
                     const float* __restrict__ Whh, const float* __restrict__ bhh,
                     float* __restrict__ cc){
    __shared__ float l3[4][256];
    __shared__ float l5[4][128];
    __shared__ float l6[4][64];
    __shared__ float lhg[4][64];
    const int lane = threadIdx.x & 63, wid = threadIdx.x >> 6;
    const int r = blockIdx.x * 4 + wid;
    for (int c = lane; c < 256; c += 64) l3[wid][c] = h3[(size_t)r*256 + c];
    for (int c = lane; c < 128; c += 64) l5[wid][c] = h5[(size_t)r*128 + c];
    l6[wid][lane] = h6[(size_t)r*64 + lane];
    WB();
    float a = A_b[lane];
    #pragma unroll 8
    for (int k = 0; k < 256; ++k) a += l3[wid][k] * A_W[k*64 + lane];
    float b = B_b[lane];
    #pragma unroll 8
    for (int k = 0; k < 128; ++k) b += l5[wid][k] * B_W[k*64 + lane];
    float z = 1.f / (1.f + expf(-(a + b)));
    float hg = z * b + (1.f - z) * a;
    lhg[wid][lane] = hg;
    WB();
    float gi0 = bih[lane], gi1 = bih[64 + lane], gi2 = bih[128 + lane];
    float gh0 = bhh[lane], gh1 = bhh[64 + lane], gh2 = bhh[128 + lane];
    #pragma unroll 4
    for (int k = 0; k < 64; ++k){
        float v6 = l6[wid][k], vh = lhg[wid][k];
        gi0 += v6 * Wih[k*192 + lane];
        gi1 += v6 * Wih[k*192 + 64 + lane];
        gi2 += v6 * Wih[k*192 + 128 + lane];
        gh0 += vh * Whh[k*192 + lane];
        gh1 += vh * Whh[k*192 + 64 + lane];
        gh2 += vh * Whh[k*192 + 128 + lane];
    }
    float rr = 1.f / (1.f + expf(-(gi0 + gh0)));
    float zz = 1.f / (1.f + expf(-(gi1 + gh1)));
    float nn = tanhf(gi2 + rr * gh2);
    cc[(size_t)r*64 + lane] = (1.f - zz) * nn + zz * hg;
}

// ---------------------------------------------------------------- fused head (pool -> f1 -> f2)
__global__ __launch_bounds__(256)
void head_kernel(const float* __restrict__ cc,
                 const float* __restrict__ f1_W, const float* __restrict__ f1_b,
                 const float* __restrict__ f2_W, const float* __restrict__ f2_b,
                 float* __restrict__ out){
    const int b = blockIdx.x, tid = threadIdx.x;
    const int c = tid & 63, grp = tid >> 6;
    __shared__ float red4[4][64];
    __shared__ float gmax[64];
    __shared__ float fgs[128];
    const float* base = cc + (size_t)(b * (NN / NG)) * 64;
    float m = -1e30f;
    #pragma unroll 8
    for (int n = grp; n < NN / NG; n += 4) m = fmaxf(m, base[n * 64 + c]);
    red4[grp][c] = m;
    __syncthreads();
    if (tid < 64)
        gmax[tid] = fmaxf(fmaxf(red4[0][tid], red4[1][tid]),
                          fmaxf(red4[2][tid], red4[3][tid]));
    __syncthreads();
    if (tid < 128){
        float acc = 0.f;
        #pragma unroll
        for (int k = 0; k < 64; ++k) acc += gmax[k] * f1_W[k * 128 + tid];
        fgs[tid] = fmaxf(acc + f1_b[tid], 0.f);
    }
    __syncthreads();
    if (tid < 120){
        float acc = 0.f;
        #pragma unroll
        for (int k = 0; k < 128; ++k) acc += fgs[k] * f2_W[k * 120 + tid];
        out[b * 120 + tid] = acc + f2_b[tid];
    }
}

// ---------------------------------------------------------------- driver
extern "C" void kernel_launch(void* const* d_in, const int* in_sizes, int n_in,
                              void* d_out, int out_size, void* d_ws, size_t ws_size,
                              hipStream_t stream){
    const float* x  = (const float*)d_in[0];
    const int* e1 = (const int*)d_in[1]; const int E1 = in_sizes[1] / 2;
    const int* e2 = (const int*)d_in[2]; const int E2 = in_sizes[2] / 2;
    const int* e3 = (const int*)d_in[3]; const int E3 = in_sizes[3] / 2;
    const float* g1_W  = (const float*)d_in[5];
    const float* g1_as = (const float*)d_in[6];
    const float* g1_ad = (const float*)d_in[7];
    const float* g1_b  = (const float*)d_in[8];
    const float* g2_W  = (const float*)d_in[9];
    const float* g2_as = (const float*)d_in[10];
    const float* g2_ad = (const float*)d_in[11];
    const float* g2_b  = (const float*)d_in[12];
    const float* gfc_W = (const float*)d_in[13];
    const float* gfc_b = (const float*)d_in[14];
    const float* gfc1_W= (const float*)d_in[15];
    const float* gfc1_b= (const float*)d_in[16];
    const float* gout_W= (const float*)d_in[17];
    const float* gout_b= (const float*)d_in[18];
    const float* c2_W  = (const float*)d_in[19];
    const float* c2_b  = (const float*)d_in[20];
    const float* c3_W  = (const float*)d_in[21];
    const float* c3_b  = (const float*)d_in[22];
    const float* A_W   = (const float*)d_in[23];
    const float* A_b   = (const float*)d_in[24];
    const float* B_W   = (const float*)d_in[25];
    const float* B_b   = (const float*)d_in[26];
    const float* Wih   = (const float*)d_in[27];
    const float* Whh   = (const float*)d_in[28];
    const float* bih   = (const float*)d_in[29];
    const float* bhh   = (const float*)d_in[30];
    const float* f1_W  = (const float*)d_in[31];
    const float* f1_b  = (const float*)d_in[32];
    const float* f2_W  = (const float*)d_in[33];
    const float* f2_b  = (const float*)d_in[34];
    float* out = (float*)d_out;

    // ---- workspace layout (~38 MB)
    int* ip = (int*)d_ws;
    int* rp1 = ip; int* rp2 = ip + 4100; int* rp3 = ip + 8200;
    float* fb = (float*)(ip + 12300);
    size_t o = 0;
    auto alloc = [&](size_t nf){ float* p = fb + o; o += nf; return p; };
    float* dinv1 = alloc(NN);
    float* dinv2 = alloc(NN);
    unsigned* Menc = (unsigned*)alloc(16);      // [0..7]=GAT1 heads, [8]=GAT2
    float* hbuf  = alloc((size_t)NN*512);       // x@g1_W [4096,512]; later houts [12288,64]
    float* al1   = alloc((size_t)NN*8);
    float* ar1   = alloc((size_t)NN*8);
    float* bigA  = alloc((size_t)3*NN*512);     // eluo3 [12288,512]; later sliced
    float* t2    = alloc((size_t)3*NN*64);      // GAT2 features [12288,64]
    float* al2   = alloc((size_t)3*NN);
    float* ar2   = alloc((size_t)3*NN);
    (void)ws_size; (void)n_in; (void)out_size;

    float* eluo3 = bigA;                        // [12288,512]
    float* g2o   = bigA;                        // [12288,64]
    float* fc1   = bigA + (size_t)786432;       // [12288,64]
    float* fc2   = bigA + (size_t)1572864;      // [12288,128]
    float* houts = hbuf;                        // [12288,64]  (hbuf dead)
    float* h1    = houts;                       // rows 0-4095
    float* h6    = houts + (size_t)2*NN*64;     // rows 8192-12287
    float* gcnx2 = bigA + (size_t)3145728;      // [8192,128]
    float* h25   = bigA + (size_t)4194304;      // [8192,128] = h2 ; h5
    float* h2    = h25;
    float* h5    = h25 + (size_t)NN*128;
    float* gcnx3 = bigA;                        // [4096,256] (g2o/fc1 dead)
    float* h3    = bigA + (size_t)1048576;      // [4096,256] (fc2 dead)
    float* ccb   = bigA + (size_t)4456448;      // [4096,64]
    const int* cols1 = e1 + E1; const int* cols2 = e2 + E2; const int* cols3 = e3 + E3;

    // ---- CSR + dinv (+ Menc init)
    rowptr3_kernel<<<(3*(NN+1)+255)/256, 256, 0, stream>>>(e1, E1, e2, E2, e3, E3, rp1, rp2, rp3);
    dinv2_kernel<<<2*NN/256, 256, 0, stream>>>(rp1, rp2, dinv1, dinv2, Menc);

    // ---- GAT pipeline (attention dots + global max fused into producing GEMMs)
    gemm_attn8_kernel<<<dim3(8, 64), 256, 0, stream>>>(x, g1_W, hbuf, g1_as, g1_ad, al1, ar1, Menc);
    gat_agg8_p2_kernel<<<6*NN, 64, 0, stream>>>(hbuf, al1, ar1, Menc,
        rp1, rp2, rp3, cols1, cols2, cols3, g1_b, eluo3);
    gemm32_attn1_kernel<<<dim3(1, 384), 256, 0, stream>>>(eluo3, g2_W, t2, g2_as, g2_ad, al2, ar2, Menc);
    gat_agg1_kernel<<<3*NN, 64, 0, stream>>>(t2, al2, ar2, Menc,
        rp1, rp2, rp3, cols1, cols2, cols3, g2_b, g2o);
    gemm32_kernel<<<dim3(1, 384), 256, 0, stream>>>(g2o, gfc_W, gfc_b, fc1, 64, 64, 1);
    gemm_kernel<<<dim3(2, 192), 256, 0, stream>>>(fc1, gfc1_W, gfc1_b, fc2, 64, 128, 1);
    gemm32_kernel<<<dim3(1, 384), 256, 0, stream>>>(fc2, gout_W, gout_b, houts, 128, 64, 1);

    // ---- GCN chain
    gemm_kernel<<<dim3(2, 128), 256, 0, stream>>>(houts, c2_W, nullptr, gcnx2, 64, 128, 0);
    gcn_agg_kernel<128><<<2*NN, 128, 0, stream>>>(gcnx2, rp1, rp2, cols1, cols2,
                                                  dinv1, dinv2, c2_b, h25);
    gemm_kernel<<<dim3(4, 64), 256, 0, stream>>>(h2, c3_W, nullptr, gcnx3, 128, 256, 0);
    gcn_agg_kernel<256><<<NN, 256, 0, stream>>>(gcnx3, rp1, rp1, cols1, cols1,
                                                dinv1, dinv1, c3_b, h3);

    // ---- fused gate + GRU
    gate_gru_kernel<<<NN/4, 256, 0, stream>>>(h3, h5, h6, A_W, A_b, B_W, B_b,
                                              Wih, bih, Whh, bhh, ccb);

    // ---- fused pool + f1 + f2
    head_kernel<<<NG, 256, 0, stream>>>(ccb, f1_W, f1_b, f2_W, f2_b, out);
}